// Round 4
// baseline (565.668 us; speedup 1.0000x reference)
//
#include <hip/hip_runtime.h>
#include <stdint.h>

// ROUND-4 RESTRUCTURE: one wave = one matrix, ZERO barriers.
// 512 blocks x 64 threads; each block owns one 64x64 matrix and 6 LDS planes
// (48KB). 2 blocks/CU -> two fully independent single-wave pipelines per CU
// whose LDS/MFMA/VALU bursts interleave freely (no lockstep, no barrier
// drain). Evidence: R1 (fewer LDS instr), R2 (2x waves), R3 (intra-wave ILP)
// all failed to move the ~1200cy/round lockstep floor; barriers are the wall.
//
// Plane format (unchanged, proven): bf16, stride 64, XOR-swizzled:
//   element [r][c] at short-index r*64 + (((c>>3) ^ (r&7))<<3) + (c&7)
//   R-plane row-major (A-frags = b128), T-plane transposed (B-frags = b128).
// Schedule (identical to the verified R0 1-periodic 6-slot schedule):
//   PA=R15, PB=T15, PC=T3 entering each iter
//   f1 m30:(PA,PB)->(PD,PE) [+trace]  f2 m60:(PD,PE)->PF [R]
//   f3 m63:(PF,PC)->PD [T]
//   gradprox (alpha from trace, T63=PD); stage m(x)->(PE=R, PF=T)
//   c1 m2:(PE,PF)->PD [R]   c2 m3:(PD,PF)->(PE,PC)
//   c3 m6:(PE,PC)->(PD,PF)  c4 m12:(PD,PF)->PE [R]
//   c5 m15:(PE,PC)->(PA,PB)
#define PL 4096  // shorts per plane

typedef unsigned int u32;
typedef unsigned short u16;
typedef float f32x4 __attribute__((ext_vector_type(4)));
typedef short short8 __attribute__((ext_vector_type(8)));

__device__ __forceinline__ u32 prm(u32 a, u32 b, u32 s) {
  return __builtin_amdgcn_perm(a, b, s);
}
__device__ __forceinline__ u32 pk(float f0, float f1) {  // {bf16 f0, bf16 f1}
  return prm(__float_as_uint(f1), __float_as_uint(f0), 0x07060302u);
}
__device__ __forceinline__ float rlo(u32 w) { return __uint_as_float(w << 16); }
__device__ __forceinline__ float rhi(u32 w) {
  return __uint_as_float(w & 0xffff0000u);
}

__device__ __forceinline__ short8 mk8(u32 w0, u32 w1, u32 w2, u32 w3) {
  union {
    u32 w[4];
    short8 s;
  } u;
  u.w[0] = w0;
  u.w[1] = w1;
  u.w[2] = w2;
  u.w[3] = w3;
  return u.s;
}

__device__ __forceinline__ void dot8(short8 a, short8 b, float& part) {
  union {
    short8 s;
    u32 w[4];
  } ua, ub;
  ua.s = a;
  ub.s = b;
#pragma unroll
  for (int w = 0; w < 4; ++w) {
    part = fmaf(rlo(ua.w[w]), rlo(ub.w[w]), part);
    part = fmaf(rhi(ua.w[w]), rhi(ub.w[w]), part);
  }
}

// Full 64x64 C = A @ B by ONE wave: 16 output tiles (4x4 bands), each a
// 2-chained 16x16x32 MFMA pair -> 32 independent chains when dual.
// Primary (a x b) -> C^T-contiguous -> T-plane; mirror (b x a) -> R-plane.
// TR: trace of (A@B) free via elementwise dot of aligned band fragments
// (A row-band f vs B col-band f), butterfly-reduced -> all lanes.
// No barrier: wave-private data, lgkmcnt ordering only.
template <bool WR, bool WT, bool TR>
__device__ __forceinline__ float mmf(const u16* __restrict__ AR,
                                     const u16* __restrict__ BT,
                                     u16* __restrict__ CR, u16* __restrict__ CT,
                                     const int (&fro)[4][2],
                                     const int (&sT)[4][4],
                                     const int (&sR)[4][4]) {
  short8 af[4][2], bf[4][2];
#pragma unroll
  for (int f = 0; f < 4; ++f) {
    af[f][0] = *(const short8*)(AR + fro[f][0]);
    af[f][1] = *(const short8*)(AR + fro[f][1]);
  }
#pragma unroll
  for (int f = 0; f < 4; ++f) {
    bf[f][0] = *(const short8*)(BT + fro[f][0]);
    bf[f][1] = *(const short8*)(BT + fro[f][1]);
  }
  float part = 0.0f;
  if (TR) {
#pragma unroll
    for (int f = 0; f < 4; ++f) {
      dot8(af[f][0], bf[f][0], part);
      dot8(af[f][1], bf[f][1], part);
    }
#pragma unroll
    for (int off = 1; off < 64; off <<= 1) part += __shfl_xor(part, off);
  }
  const f32x4 Z = {0.0f, 0.0f, 0.0f, 0.0f};
#pragma unroll
  for (int a = 0; a < 4; ++a)
#pragma unroll
    for (int b = 0; b < 4; ++b) {
      if (WT) {
        f32x4 acc = __builtin_amdgcn_mfma_f32_16x16x32_bf16(af[a][0], bf[b][0],
                                                            Z, 0, 0, 0);
        acc = __builtin_amdgcn_mfma_f32_16x16x32_bf16(af[a][1], bf[b][1], acc,
                                                      0, 0, 0);
        *(uint2*)(CT + sT[a][b]) =
            make_uint2(pk(acc[0], acc[1]), pk(acc[2], acc[3]));
      }
      if (WR) {
        f32x4 acc = __builtin_amdgcn_mfma_f32_16x16x32_bf16(bf[b][0], af[a][0],
                                                            Z, 0, 0, 0);
        acc = __builtin_amdgcn_mfma_f32_16x16x32_bf16(bf[b][1], af[a][1], acc,
                                                      0, 0, 0);
        *(uint2*)(CR + sR[a][b]) =
            make_uint2(pk(acc[0], acc[1]), pk(acc[2], acc[3]));
      }
    }
  return part;
}

__global__ __launch_bounds__(64, 1) void dag_iter_kernel(
    const float* __restrict__ adj, float* __restrict__ out) {
  __shared__ __align__(16) u16 BUF[6 * PL];
  u16* PA = BUF;
  u16* PB = BUF + PL;
  u16* PC = BUF + 2 * PL;
  u16* PD = BUF + 3 * PL;
  u16* PE = BUF + 4 * PL;
  u16* PF = BUF + 5 * PL;

  const int lane = (int)threadIdx.x & 63;
  const int l15 = lane & 15;
  const int grp = lane >> 4;
  const int l7 = l15 & 7;
  // Elementwise ownership: lane owns the 8x8 block (rows rblk*8.., cols
  // cblk*8..) -> per-plane block I/O is 8 conflict-free b128 ops.
  const int rblk = lane >> 3;
  const int cblk = lane & 7;

  // MFMA fragment read offsets: band f (16 rows), k-half q. Identical
  // formula for A-frags (R-plane rows) and B-frags (T-plane rows).
  int fro[4][2];
#pragma unroll
  for (int f = 0; f < 4; ++f)
#pragma unroll
    for (int q = 0; q < 2; ++q)
      fro[f][q] = (f * 16 + l15) * 64 + ((((q << 2) + grp) ^ l7) << 3);
  // Product-tile store offsets (uint2 per lane), tile (a=row band, b=col).
  int sT[4][4], sR[4][4];
#pragma unroll
  for (int a = 0; a < 4; ++a)
#pragma unroll
    for (int b = 0; b < 4; ++b) {
      sT[a][b] = (16 * b + l15) * 64 + (((2 * a + (grp >> 1)) ^ l7) << 3) +
                 ((grp & 1) << 2);
      sR[a][b] = (16 * a + l15) * 64 + (((2 * b + (grp >> 1)) ^ l7) << 3) +
                 ((grp & 1) << 2);
    }
  // Elementwise block addresses: R-pattern rows and T-pattern rows.
  int erow[8], ecol[8];
#pragma unroll
  for (int i = 0; i < 8; ++i) {
    const int r = rblk * 8 + i;
    erow[i] = r * 64 + ((cblk ^ (r & 7)) << 3);
    const int c = cblk * 8 + i;
    ecol[i] = c * 64 + ((rblk ^ (c & 7)) << 3);
  }

  const float* src = adj + (size_t)blockIdx.x * 4096;
  float x[8][8], sc[8][8];
#pragma unroll
  for (int i = 0; i < 8; ++i) {
    f32x4 v0 = *(const f32x4*)(src + (rblk * 8 + i) * 64 + cblk * 8);
    f32x4 v1 = *(const f32x4*)(src + (rblk * 8 + i) * 64 + cblk * 8 + 4);
#pragma unroll
    for (int j = 0; j < 4; ++j) {
      x[i][j] = v0[j];
      x[i][4 + j] = v1[j];
      sc[i][j] = (v0[j] > 0.5f) ? v0[j] : 0.0f;
      sc[i][4 + j] = (v1[j] > 0.5f) ? v1[j] : 0.0f;
    }
  }
  float alpha = 0.0f;

  auto prox1 = [&](float til, int i, int j) {
    float ax = fabsf(til) - 2e-5f;
    float nx = ax > 0.0f ? ax : 0.0f;
    x[i][j] = nx > 1.0f ? 1.0f : nx;
  };
  auto stage = [&]() {  // m = I + x.*x/64 -> PE (R-plane), PF (T-plane)
    float m[8][8];
#pragma unroll
    for (int i = 0; i < 8; ++i)
#pragma unroll
      for (int j = 0; j < 8; ++j)
        m[i][j] = fmaf(x[i][j] * x[i][j], 0.015625f,
                       (rblk * 8 + i == cblk * 8 + j) ? 1.0f : 0.0f);
#pragma unroll
    for (int i = 0; i < 8; ++i)
      *(short8*)(PE + erow[i]) =
          mk8(pk(m[i][0], m[i][1]), pk(m[i][2], m[i][3]), pk(m[i][4], m[i][5]),
              pk(m[i][6], m[i][7]));
#pragma unroll
    for (int j = 0; j < 8; ++j)
      *(short8*)(PF + ecol[j]) =
          mk8(pk(m[0][j], m[1][j]), pk(m[2][j], m[3][j]), pk(m[4][j], m[5][j]),
              pk(m[6][j], m[7][j]));
  };
  auto gradprox = [&](float tr) {  // T63 in PD; tr = tr(m30)
    alpha = fmaf(0.01f, tr * 0.015625f - 1.0f, alpha);
    const float a2 = alpha * 0.03125f;  // 2*alpha/64
#pragma unroll
    for (int i = 0; i < 8; ++i) {
      short8 w = *(const short8*)(PD + erow[i]);
      union {
        short8 s;
        u32 u[4];
      } uw;
      uw.s = w;
#pragma unroll
      for (int j = 0; j < 4; ++j) {
        float plo = rlo(uw.u[j]), phi = rhi(uw.u[j]);
        float g0 = fmaf(a2 * x[i][2 * j], plo, -sc[i][2 * j]);
        float g1 = fmaf(a2 * x[i][2 * j + 1], phi, -sc[i][2 * j + 1]);
        prox1(fmaf(-0.01f, g0, x[i][2 * j]), i, 2 * j);
        prox1(fmaf(-0.01f, g1, x[i][2 * j + 1]), i, 2 * j + 1);
      }
    }
  };
  auto chain5 = [&]() {  // sources: PE=R(m), PF=T(m)
    mmf<true, false, false>(PE, PF, PD, PD, fro, sT, sR);  // c1: m2 -> R (PD)
    mmf<true, true, false>(PD, PF, PE, PC, fro, sT, sR);   // c2: m3 -> (R3,T3)
    mmf<true, true, false>(PE, PC, PD, PF, fro, sT, sR);   // c3: m6
    mmf<true, false, false>(PD, PF, PE, PE, fro, sT, sR);  // c4: m12 -> R
    mmf<true, true, false>(PE, PC, PA, PB, fro, sT, sR);   // c5: m15 ->(PA,PB)
  };
  auto front = [&]() -> float {  // returns tr(m30)
    float tr =
        mmf<true, true, true>(PA, PB, PD, PE, fro, sT, sR);  // f1: m30 + trace
    mmf<true, false, false>(PD, PE, PF, PF, fro, sT, sR);    // f2: m60 -> R
    mmf<false, true, false>(PF, PC, PD, PD, fro, sT, sR);    // f3: m63 -> T
    return tr;
  };

  // ---- iteration 0: alpha == 0 -> grad = -scores ----
  {
#pragma unroll
    for (int i = 0; i < 8; ++i)
#pragma unroll
      for (int j = 0; j < 8; ++j)
        prox1(fmaf(0.01f, sc[i][j], x[i][j]), i, j);
    stage();
    chain5();
  }
  // ---- iterations 1..48 ----
  for (int it = 0; it < 48; ++it) {
    float tr = front();
    gradprox(tr);
    stage();
    chain5();
  }
  // ---- iteration 49: no trailing stage/chain ----
  {
    float tr = front();
    gradprox(tr);
  }

  float* dst = out + (size_t)blockIdx.x * 4096;
#pragma unroll
  for (int i = 0; i < 8; ++i) {
    f32x4 v0, v1;
#pragma unroll
    for (int j = 0; j < 4; ++j) {
      v0[j] = (x[i][j] > 0.5f) ? x[i][j] : 0.0f;
      v1[j] = (x[i][4 + j] > 0.5f) ? x[i][4 + j] : 0.0f;
    }
    *(f32x4*)(dst + (rblk * 8 + i) * 64 + cblk * 8) = v0;
    *(f32x4*)(dst + (rblk * 8 + i) * 64 + cblk * 8 + 4) = v1;
  }
}

extern "C" void kernel_launch(void* const* d_in, const int* in_sizes, int n_in,
                              void* d_out, int out_size, void* d_ws,
                              size_t ws_size, hipStream_t stream) {
  const float* adj = (const float*)d_in[0];
  float* out = (float*)d_out;
  const int nbatch = in_sizes[0] / 4096;  // 512
  dag_iter_kernel<<<nbatch, 64, 0, stream>>>(adj, out);
}

// Round 5
// 245.182 us; speedup vs baseline: 2.3071x; 2.3071x over previous
//
#include <hip/hip_runtime.h>
#include <stdint.h>

// ROUND-5: row-band ownership + in-register A-fragment forwarding.
// 512 blocks x 256 thr (4 waves), 2 blocks/CU (proven best shell, R0/R2).
// Wave w owns row band w (rows 16w..16w+15) of EVERY product. The mirror
// product mfma(b,a) = C^T leaves C's rows lane-local; 8 pk + 4x
// (permlane32_swap + permlane16_swap) rebuild the next product's A-fragments
// entirely in registers -> the serial power chain never round-trips LDS for
// its A operand. Only T-planes (B operands) + elementwise patches use LDS.
// Barriers: 9 -> 6 per iteration; LDS: 6 planes -> 4 planes (32KB).
// Numerics bit-identical to R0 (same products, same MFMA accumulation order,
// same pk rounding points).
//
// Plane format (proven): bf16, stride 64, XOR-swizzled:
//   element [X][Y] at short-index X*64 + (((Y>>3) ^ (X&7))<<3) + (Y&7)
//   T-plane of M: plane[X=c][Y=r] = M[r][c].
// Slots: S0: R(m) [stage->c1] then T15 [c5->f1]
//        S1: T(m) [stage->c1] then T30 [f1->f2]
//        S2: T3 [c2->c3] then T63 [f3->gradprox]
//        S3: T6 [c3->c4]
// Schedule/iter: c1 m2 (mirror) ; c2 m3 (dual -> T3, barrier B)
//   c3 m6 (dual -> T6, barrier C; bf3 reg-cache of T3)
//   c4 m12 (mirror) ; c5 m15 (dual -> T15, barrier D)
//   f1 m30 (dual -> T30 + free trace, barrier E) ; f2 m60 (mirror)
//   f3 m63 (primary only -> T63, barrier F)
//   gradprox (reads T63) ; stage (R(m)->S0, T(m)->S1, barrier A)
#define PL 4096  // shorts per plane

typedef unsigned int u32;
typedef unsigned short u16;
typedef float f32x4 __attribute__((ext_vector_type(4)));
typedef short short8 __attribute__((ext_vector_type(8)));
typedef unsigned int u32x2 __attribute__((ext_vector_type(2)));

__device__ __forceinline__ u32 prm(u32 a, u32 b, u32 s) {
  return __builtin_amdgcn_perm(a, b, s);
}
__device__ __forceinline__ u32 pk(float f0, float f1) {  // {bf16 f0, bf16 f1}
  return prm(__float_as_uint(f1), __float_as_uint(f0), 0x07060302u);
}
__device__ __forceinline__ float rlo(u32 w) { return __uint_as_float(w << 16); }
__device__ __forceinline__ float rhi(u32 w) {
  return __uint_as_float(w & 0xffff0000u);
}
__device__ __forceinline__ short8 mk8(u32 w0, u32 w1, u32 w2, u32 w3) {
  union {
    u32 w[4];
    short8 s;
  } u;
  u.w[0] = w0;
  u.w[1] = w1;
  u.w[2] = w2;
  u.w[3] = w3;
  return u.s;
}
__device__ __forceinline__ void dot8(short8 a, short8 b, float& part) {
  union {
    short8 s;
    u32 w[4];
  } ua, ub;
  ua.s = a;
  ub.s = b;
#pragma unroll
  for (int w = 0; w < 4; ++w) {
    part = fmaf(rlo(ua.w[w]), rlo(ub.w[w]), part);
    part = fmaf(rhi(ua.w[w]), rhi(ub.w[w]), part);
  }
}
__device__ __forceinline__ f32x4 MF(short8 a, short8 b, f32x4 c) {
  return __builtin_amdgcn_mfma_f32_16x16x32_bf16(a, b, c, 0, 0, 0);
}

struct AF {
  short8 a0, a1;
};  // A-frags of the wave's row band: k-halves 0..31, 32..63
struct BF8 {
  short8 b[4][2];
};  // B-frags: 4 col tiles x 2 k-halves

// Group-level redistribution (16-lane groups g=0..3 of the wave):
//   x = [U@g0, U@g2, V@g0, V@g2], y = [U@g1, U@g3, V@g1, V@g3]
__device__ __forceinline__ void dist2(u32 U, u32 V, u32& x, u32& y) {
  u32x2 s = __builtin_amdgcn_permlane32_swap(U, V, false, false);
  // s[0] = [U0,U1,V0,V1], s[1] = [U2,U3,V2,V3]
#if __has_builtin(__builtin_amdgcn_permlane16_swap)
  u32x2 t = __builtin_amdgcn_permlane16_swap(s[0], s[1], false, false);
  x = t[0];  // [U0,U2,V0,V2]
  y = t[1];  // [U1,U3,V1,V3]
#else
  u32 a = s[0], b = s[1];
  u32 bx = (u32)__shfl_xor((int)b, 16);
  u32 ax = (u32)__shfl_xor((int)a, 16);
  const bool odd = ((threadIdx.x >> 4) & 1) != 0;
  x = odd ? bx : a;
  y = odd ? b : ax;
#endif
}

// Mirror acc (4 tiles, lane = row 16w+l15, cols 16b+4g+{0..3}) -> A-frags
// (lane = row, af[kh] word j = cols 32kh+8g+2j+{0,1}).
__device__ __forceinline__ AF macc_to_af(const f32x4 (&m)[4]) {
  u32 P0[4], P1[4];
#pragma unroll
  for (int b = 0; b < 4; ++b) {
    P0[b] = pk(m[b][0], m[b][1]);
    P1[b] = pk(m[b][2], m[b][3]);
  }
  u32 W0[4], W1[4];
  dist2(P0[0], P0[1], W0[0], W0[2]);
  dist2(P1[0], P1[1], W0[1], W0[3]);
  dist2(P0[2], P0[3], W1[0], W1[2]);
  dist2(P1[2], P1[3], W1[1], W1[3]);
  AF r;
  r.a0 = mk8(W0[0], W0[1], W0[2], W0[3]);
  r.a1 = mk8(W1[0], W1[1], W1[2], W1[3]);
  return r;
}

__global__ __launch_bounds__(256, 2) void dag_iter_kernel(
    const float* __restrict__ adj, float* __restrict__ out) {
  __shared__ __align__(16) u16 BUF[4 * PL];
  __shared__ float red[4];
  u16* S0 = BUF;
  u16* S1 = BUF + PL;
  u16* S2 = BUF + 2 * PL;
  u16* S3 = BUF + 3 * PL;

  // De-phase the two co-resident blocks on a CU.
  if ((blockIdx.x >> 8) & 1) __builtin_amdgcn_s_sleep(11);

  const int tid = (int)threadIdx.x;
  const int lane = tid & 63;
  const int wv = tid >> 6;  // row band 0..3
  const int l15 = lane & 15;
  const int grp = lane >> 4;
  const int l7 = l15 & 7;
  const int r0 = (tid & 15) << 2;  // elementwise 4x4 patch
  const int c0 = (tid >> 4) << 2;

  // A-frag read (c1 only, from R(m)): row 16w+l15, k-chunk 4kh+grp.
  int ra[2];
#pragma unroll
  for (int kh = 0; kh < 2; ++kh)
    ra[kh] = (16 * wv + l15) * 64 + ((((kh << 2) + grp) ^ l7) << 3);
  // B-frag reads from a T-plane: tile b rows 16b+l15 (row&7 == l7).
  int rb[4][2];
#pragma unroll
  for (int b = 0; b < 4; ++b)
#pragma unroll
    for (int kh = 0; kh < 2; ++kh)
      rb[b][kh] = (16 * b + l15) * 64 + ((((kh << 2) + grp) ^ l7) << 3);
  // Primary-acc T-plane store: T[16b+l15][16w+4grp+{0..3}] (uint2).
  int sT[4];
#pragma unroll
  for (int b = 0; b < 4; ++b)
    sT[b] = (16 * b + l15) * 64 + (((2 * wv + (grp >> 1)) ^ l7) << 3) +
            ((grp & 1) << 2);
  // Elementwise patch addresses.
  int prow[4], pcol[4];
#pragma unroll
  for (int i = 0; i < 4; ++i) {
    prow[i] = (r0 + i) * 64 + ((((c0 >> 3) ^ ((r0 + i) & 7))) << 3) + (c0 & 7);
    pcol[i] = (c0 + i) * 64 + ((((r0 >> 3) ^ ((c0 + i) & 7))) << 3) + (r0 & 7);
  }

  const float* src = adj + (size_t)blockIdx.x * 4096;
  float x[4][4], sc[4][4];
#pragma unroll
  for (int i = 0; i < 4; ++i) {
    f32x4 v = *(const f32x4*)(src + (r0 + i) * 64 + c0);
#pragma unroll
    for (int j = 0; j < 4; ++j) {
      x[i][j] = v[j];
      sc[i][j] = (v[j] > 0.5f) ? v[j] : 0.0f;
    }
  }
  float alpha = 0.0f;
  AF af;    // af(m15): c5 -> f1
  BF8 bf3;  // B-frags of m3 (T3): c3 -> c5 -> f3

  auto loadBF = [&](const u16* P) {
    BF8 f;
#pragma unroll
    for (int b = 0; b < 4; ++b) {
      f.b[b][0] = *(const short8*)(P + rb[b][0]);
      f.b[b][1] = *(const short8*)(P + rb[b][1]);
    }
    return f;
  };
  auto mirrorAF = [&](const AF& a, const BF8& bf) {  // rows of A*M -> regs
    const f32x4 Z = {0.0f, 0.0f, 0.0f, 0.0f};
    f32x4 m[4];
#pragma unroll
    for (int b = 0; b < 4; ++b) {
      m[b] = MF(bf.b[b][0], a.a0, Z);
      m[b] = MF(bf.b[b][1], a.a1, m[b]);
    }
    return macc_to_af(m);
  };
  auto primaryT = [&](const AF& a, const BF8& bf, u16* P) {  // cols -> T-plane
    const f32x4 Z = {0.0f, 0.0f, 0.0f, 0.0f};
#pragma unroll
    for (int b = 0; b < 4; ++b) {
      f32x4 p = MF(a.a0, bf.b[b][0], Z);
      p = MF(a.a1, bf.b[b][1], p);
      *(uint2*)(P + sT[b]) = make_uint2(pk(p[0], p[1]), pk(p[2], p[3]));
    }
  };
  auto traceP = [&](const AF& a, const BF8& bf) {  // tr(m30) from m15 frags
    short8 c0s = bf.b[0][0], c1s = bf.b[0][1];
    if (wv == 1) {
      c0s = bf.b[1][0];
      c1s = bf.b[1][1];
    } else if (wv == 2) {
      c0s = bf.b[2][0];
      c1s = bf.b[2][1];
    } else if (wv == 3) {
      c0s = bf.b[3][0];
      c1s = bf.b[3][1];
    }
    float part = 0.0f;
    dot8(a.a0, c0s, part);
    dot8(a.a1, c1s, part);
#pragma unroll
    for (int off = 1; off < 64; off <<= 1) part += __shfl_xor(part, off);
    if (lane == 0) red[wv] = part;
  };

  auto prox = [&](float til[4][4]) {
#pragma unroll
    for (int i = 0; i < 4; ++i)
#pragma unroll
      for (int j = 0; j < 4; ++j) {
        float ax = fabsf(til[i][j]) - 2e-5f;
        float nx = ax > 0.0f ? ax : 0.0f;
        x[i][j] = nx > 1.0f ? 1.0f : nx;
      }
  };
  auto stage = [&]() {  // m = I + x.*x/64 -> S0 (R-plane), S1 (T-plane)
    float m[4][4];
#pragma unroll
    for (int i = 0; i < 4; ++i)
#pragma unroll
      for (int j = 0; j < 4; ++j)
        m[i][j] = fmaf(x[i][j] * x[i][j], 0.015625f,
                       (r0 + i == c0 + j) ? 1.0f : 0.0f);
#pragma unroll
    for (int i = 0; i < 4; ++i)
      *(uint2*)(S0 + prow[i]) =
          make_uint2(pk(m[i][0], m[i][1]), pk(m[i][2], m[i][3]));
#pragma unroll
    for (int j = 0; j < 4; ++j)
      *(uint2*)(S1 + pcol[j]) =
          make_uint2(pk(m[0][j], m[1][j]), pk(m[2][j], m[3][j]));
    __syncthreads();  // A
  };
  auto gradprox = [&]() {  // polyT[i][j] = T63-plane[r0+i][c0+j] (S2)
    float tr = red[0] + red[1] + red[2] + red[3];
    alpha = fmaf(0.01f, tr * 0.015625f - 1.0f, alpha);
    const float a2 = alpha * 0.03125f;  // 2*alpha/64
    float til[4][4];
#pragma unroll
    for (int i = 0; i < 4; ++i) {
      uint2 w = *(const uint2*)(S2 + prow[i]);
      float pt[4] = {rlo(w.x), rhi(w.x), rlo(w.y), rhi(w.y)};
#pragma unroll
      for (int j = 0; j < 4; ++j) {
        float g = fmaf(a2 * x[i][j], pt[j], -sc[i][j]);
        til[i][j] = fmaf(-0.01f, g, x[i][j]);
      }
    }
    prox(til);
  };

  auto chain5 = [&]() {  // from S0=R(m), S1=T(m): build m15 (af) + planes
    AF afm;
    afm.a0 = *(const short8*)(S0 + ra[0]);
    afm.a1 = *(const short8*)(S0 + ra[1]);
    BF8 bm = loadBF(S1);
    AF af2 = mirrorAF(afm, bm);  // c1: m2 (mirror only)
    AF af3 = mirrorAF(af2, bm);  // c2: m3 mirror
    primaryT(af2, bm, S2);       // c2: m3 primary -> T3
    __syncthreads();             // B
    bf3 = loadBF(S2);
    AF af6 = mirrorAF(af3, bf3);  // c3: m6 mirror
    primaryT(af3, bf3, S3);       // c3: m6 primary -> T6
    __syncthreads();              // C
    BF8 b6 = loadBF(S3);
    AF af12 = mirrorAF(af6, b6);  // c4: m12 (mirror only)
    af = mirrorAF(af12, bf3);     // c5: m15 mirror (kept for f1)
    primaryT(af12, bf3, S0);      // c5: m15 primary -> T15
    __syncthreads();              // D
  };
  auto front = [&]() {  // m30, m60, m63 -> T63 in S2
    BF8 b15 = loadBF(S0);
    traceP(af, b15);              // free tr(m30)
    AF af30 = mirrorAF(af, b15);  // f1: m30 mirror
    primaryT(af, b15, S1);        // f1: m30 primary -> T30
    __syncthreads();              // E
    BF8 b30 = loadBF(S1);
    AF af60 = mirrorAF(af30, b30);  // f2: m60 (mirror only)
    primaryT(af60, bf3, S2);        // f3: m63 primary -> T63
    __syncthreads();                // F
  };

  // ---- iteration 0: alpha == 0 -> grad = -scores ----
  {
    float til[4][4];
#pragma unroll
    for (int i = 0; i < 4; ++i)
#pragma unroll
      for (int j = 0; j < 4; ++j) til[i][j] = fmaf(0.01f, sc[i][j], x[i][j]);
    prox(til);
    stage();
    chain5();
  }
  // ---- iterations 1..48 ----
  for (int it = 0; it < 48; ++it) {
    front();
    gradprox();
    stage();
    chain5();
  }
  // ---- iteration 49: no trailing stage/chain ----
  front();
  gradprox();

  float* dst = out + (size_t)blockIdx.x * 4096;
#pragma unroll
  for (int i = 0; i < 4; ++i) {
    f32x4 v;
#pragma unroll
    for (int j = 0; j < 4; ++j) v[j] = (x[i][j] > 0.5f) ? x[i][j] : 0.0f;
    *(f32x4*)(dst + (r0 + i) * 64 + c0) = v;
  }
}

extern "C" void kernel_launch(void* const* d_in, const int* in_sizes, int n_in,
                              void* d_out, int out_size, void* d_ws,
                              size_t ws_size, hipStream_t stream) {
  const float* adj = (const float*)d_in[0];
  float* out = (float*)d_out;
  const int nbatch = in_sizes[0] / 4096;  // 512
  dag_iter_kernel<<<nbatch, 256, 0, stream>>>(adj, out);
}

// Round 6
// 240.713 us; speedup vs baseline: 2.3500x; 1.0186x over previous
//
#include <hip/hip_runtime.h>
#include <stdint.h>

// ROUND-6: R5 (row-band ownership + in-register A-forwarding) with the power
// chain RE-ASSOCIATED so B-operands come from only three synced planes:
//   T(m):  m2 = m*m, m3 = m2*m
//   T3  :  m6 = m3*m3, m9 = m6*m3, m12 = m9*m3, m15 = m12*m3, m63 = m60*m3
//   T15 :  m30 = m15*m15, m45 = m30*m15, m60 = m45*m15
// -> barriers 6 -> 4 per iteration; T6/T30 planes and their store/reload
// rounds deleted. MFMA count unchanged (96/iter/wave). Exponents:
// 2,3,6,9,12,15,30,45,60,63. tr(m30) = sum m15 .* m15^T (unchanged trick).
//
// Shell (proven R0/R5): 512 blocks x 256 thr (4 waves), 2 blocks/CU,
// wave w owns row band w of every product; mirror mfma(b,a) leaves product
// rows lane-local; 8 pk + 4x(permlane32_swap+permlane16_swap) rebuild the
// next A-fragments in registers.
//
// Plane format: bf16, stride 64, XOR-swizzled:
//   element [X][Y] at short-index X*64 + (((Y>>3) ^ (X&7))<<3) + (Y&7)
//   T-plane of M: plane[X=c][Y=r] = M[r][c].
// Slots: S0=R(m) [stage->c1]   S1=T(m) [stage->m2,m3]
//        S2=T3 [->bf3 cache] then T63 [->gradprox]   S3=T15 [->front]
// Barriers/iter: A (stage), B (T3), D (T15), F (T63).
#define PL 4096  // shorts per plane

typedef unsigned int u32;
typedef unsigned short u16;
typedef float f32x4 __attribute__((ext_vector_type(4)));
typedef short short8 __attribute__((ext_vector_type(8)));
typedef unsigned int u32x2 __attribute__((ext_vector_type(2)));

__device__ __forceinline__ u32 prm(u32 a, u32 b, u32 s) {
  return __builtin_amdgcn_perm(a, b, s);
}
__device__ __forceinline__ u32 pk(float f0, float f1) {  // {bf16 f0, bf16 f1}
  return prm(__float_as_uint(f1), __float_as_uint(f0), 0x07060302u);
}
__device__ __forceinline__ float rlo(u32 w) { return __uint_as_float(w << 16); }
__device__ __forceinline__ float rhi(u32 w) {
  return __uint_as_float(w & 0xffff0000u);
}
__device__ __forceinline__ short8 mk8(u32 w0, u32 w1, u32 w2, u32 w3) {
  union {
    u32 w[4];
    short8 s;
  } u;
  u.w[0] = w0;
  u.w[1] = w1;
  u.w[2] = w2;
  u.w[3] = w3;
  return u.s;
}
__device__ __forceinline__ void dot8(short8 a, short8 b, float& part) {
  union {
    short8 s;
    u32 w[4];
  } ua, ub;
  ua.s = a;
  ub.s = b;
#pragma unroll
  for (int w = 0; w < 4; ++w) {
    part = fmaf(rlo(ua.w[w]), rlo(ub.w[w]), part);
    part = fmaf(rhi(ua.w[w]), rhi(ub.w[w]), part);
  }
}
__device__ __forceinline__ f32x4 MF(short8 a, short8 b, f32x4 c) {
  return __builtin_amdgcn_mfma_f32_16x16x32_bf16(a, b, c, 0, 0, 0);
}

struct AF {
  short8 a0, a1;
};  // A-frags of the wave's row band: k-halves 0..31, 32..63
struct BF8 {
  short8 b[4][2];
};  // B-frags: 4 col tiles x 2 k-halves

// Group-level redistribution (16-lane groups g=0..3 of the wave):
//   x = [U@g0, U@g2, V@g0, V@g2], y = [U@g1, U@g3, V@g1, V@g3]
__device__ __forceinline__ void dist2(u32 U, u32 V, u32& x, u32& y) {
  u32x2 s = __builtin_amdgcn_permlane32_swap(U, V, false, false);
  // s[0] = [U0,U1,V0,V1], s[1] = [U2,U3,V2,V3]
#if __has_builtin(__builtin_amdgcn_permlane16_swap)
  u32x2 t = __builtin_amdgcn_permlane16_swap(s[0], s[1], false, false);
  x = t[0];  // [U0,U2,V0,V2]
  y = t[1];  // [U1,U3,V1,V3]
#else
  u32 a = s[0], b = s[1];
  u32 bx = (u32)__shfl_xor((int)b, 16);
  u32 ax = (u32)__shfl_xor((int)a, 16);
  const bool odd = ((threadIdx.x >> 4) & 1) != 0;
  x = odd ? bx : a;
  y = odd ? b : ax;
#endif
}

// Mirror acc (4 tiles, lane = row 16w+l15, cols 16b+4g+{0..3}) -> A-frags
// (lane = row, af[kh] word j = cols 32kh+8g+2j+{0,1}).
__device__ __forceinline__ AF macc_to_af(const f32x4 (&m)[4]) {
  u32 P0[4], P1[4];
#pragma unroll
  for (int b = 0; b < 4; ++b) {
    P0[b] = pk(m[b][0], m[b][1]);
    P1[b] = pk(m[b][2], m[b][3]);
  }
  u32 W0[4], W1[4];
  dist2(P0[0], P0[1], W0[0], W0[2]);
  dist2(P1[0], P1[1], W0[1], W0[3]);
  dist2(P0[2], P0[3], W1[0], W1[2]);
  dist2(P1[2], P1[3], W1[1], W1[3]);
  AF r;
  r.a0 = mk8(W0[0], W0[1], W0[2], W0[3]);
  r.a1 = mk8(W1[0], W1[1], W1[2], W1[3]);
  return r;
}

__global__ __launch_bounds__(256, 2) void dag_iter_kernel(
    const float* __restrict__ adj, float* __restrict__ out) {
  __shared__ __align__(16) u16 BUF[4 * PL];
  __shared__ float red[4];
  u16* S0 = BUF;
  u16* S1 = BUF + PL;
  u16* S2 = BUF + 2 * PL;
  u16* S3 = BUF + 3 * PL;

  // De-phase the two co-resident blocks on a CU.
  if ((blockIdx.x >> 8) & 1) __builtin_amdgcn_s_sleep(11);

  const int tid = (int)threadIdx.x;
  const int lane = tid & 63;
  const int wv = tid >> 6;  // row band 0..3
  const int l15 = lane & 15;
  const int grp = lane >> 4;
  const int l7 = l15 & 7;
  const int r0 = (tid & 15) << 2;  // elementwise 4x4 patch
  const int c0 = (tid >> 4) << 2;

  // A-frag read (c1 only, from R(m)): row 16w+l15, k-chunk 4kh+grp.
  int ra[2];
#pragma unroll
  for (int kh = 0; kh < 2; ++kh)
    ra[kh] = (16 * wv + l15) * 64 + ((((kh << 2) + grp) ^ l7) << 3);
  // B-frag reads from a T-plane: tile b rows 16b+l15 (row&7 == l7).
  int rb[4][2];
#pragma unroll
  for (int b = 0; b < 4; ++b)
#pragma unroll
    for (int kh = 0; kh < 2; ++kh)
      rb[b][kh] = (16 * b + l15) * 64 + ((((kh << 2) + grp) ^ l7) << 3);
  // Primary-acc T-plane store: T[16b+l15][16w+4grp+{0..3}] (uint2).
  int sT[4];
#pragma unroll
  for (int b = 0; b < 4; ++b)
    sT[b] = (16 * b + l15) * 64 + (((2 * wv + (grp >> 1)) ^ l7) << 3) +
            ((grp & 1) << 2);
  // Elementwise patch addresses.
  int prow[4], pcol[4];
#pragma unroll
  for (int i = 0; i < 4; ++i) {
    prow[i] = (r0 + i) * 64 + ((((c0 >> 3) ^ ((r0 + i) & 7))) << 3) + (c0 & 7);
    pcol[i] = (c0 + i) * 64 + ((((r0 >> 3) ^ ((c0 + i) & 7))) << 3) + (r0 & 7);
  }

  const float* src = adj + (size_t)blockIdx.x * 4096;
  float x[4][4], sc[4][4];
#pragma unroll
  for (int i = 0; i < 4; ++i) {
    f32x4 v = *(const f32x4*)(src + (r0 + i) * 64 + c0);
#pragma unroll
    for (int j = 0; j < 4; ++j) {
      x[i][j] = v[j];
      sc[i][j] = (v[j] > 0.5f) ? v[j] : 0.0f;
    }
  }
  float alpha = 0.0f;
  AF af;    // af(m15): chain -> front
  BF8 bf3;  // B-frags of m3 (T3): reg cache, chain -> m63 primary

  auto loadBF = [&](const u16* P) {
    BF8 f;
#pragma unroll
    for (int b = 0; b < 4; ++b) {
      f.b[b][0] = *(const short8*)(P + rb[b][0]);
      f.b[b][1] = *(const short8*)(P + rb[b][1]);
    }
    return f;
  };
  auto mirrorAF = [&](const AF& a, const BF8& bf) {  // rows of A*M -> regs
    const f32x4 Z = {0.0f, 0.0f, 0.0f, 0.0f};
    f32x4 m[4];
#pragma unroll
    for (int b = 0; b < 4; ++b) {
      m[b] = MF(bf.b[b][0], a.a0, Z);
      m[b] = MF(bf.b[b][1], a.a1, m[b]);
    }
    return macc_to_af(m);
  };
  auto primaryT = [&](const AF& a, const BF8& bf, u16* P) {  // cols -> T-plane
    const f32x4 Z = {0.0f, 0.0f, 0.0f, 0.0f};
#pragma unroll
    for (int b = 0; b < 4; ++b) {
      f32x4 p = MF(a.a0, bf.b[b][0], Z);
      p = MF(a.a1, bf.b[b][1], p);
      *(uint2*)(P + sT[b]) = make_uint2(pk(p[0], p[1]), pk(p[2], p[3]));
    }
  };
  auto traceP = [&](const AF& a, const BF8& bf) {  // tr(m30) from m15 frags
    short8 c0s = bf.b[0][0], c1s = bf.b[0][1];
    if (wv == 1) {
      c0s = bf.b[1][0];
      c1s = bf.b[1][1];
    } else if (wv == 2) {
      c0s = bf.b[2][0];
      c1s = bf.b[2][1];
    } else if (wv == 3) {
      c0s = bf.b[3][0];
      c1s = bf.b[3][1];
    }
    float part = 0.0f;
    dot8(a.a0, c0s, part);
    dot8(a.a1, c1s, part);
#pragma unroll
    for (int off = 1; off < 64; off <<= 1) part += __shfl_xor(part, off);
    if (lane == 0) red[wv] = part;
  };

  auto prox = [&](float til[4][4]) {
#pragma unroll
    for (int i = 0; i < 4; ++i)
#pragma unroll
      for (int j = 0; j < 4; ++j) {
        float ax = fabsf(til[i][j]) - 2e-5f;
        float nx = ax > 0.0f ? ax : 0.0f;
        x[i][j] = nx > 1.0f ? 1.0f : nx;
      }
  };
  auto stage = [&]() {  // m = I + x.*x/64 -> S0 (R-plane), S1 (T-plane)
    float m[4][4];
#pragma unroll
    for (int i = 0; i < 4; ++i)
#pragma unroll
      for (int j = 0; j < 4; ++j)
        m[i][j] = fmaf(x[i][j] * x[i][j], 0.015625f,
                       (r0 + i == c0 + j) ? 1.0f : 0.0f);
#pragma unroll
    for (int i = 0; i < 4; ++i)
      *(uint2*)(S0 + prow[i]) =
          make_uint2(pk(m[i][0], m[i][1]), pk(m[i][2], m[i][3]));
#pragma unroll
    for (int j = 0; j < 4; ++j)
      *(uint2*)(S1 + pcol[j]) =
          make_uint2(pk(m[0][j], m[1][j]), pk(m[2][j], m[3][j]));
    __syncthreads();  // A
  };
  auto gradprox = [&]() {  // polyT[i][j] = T63-plane[r0+i][c0+j] (S2)
    float tr = red[0] + red[1] + red[2] + red[3];
    alpha = fmaf(0.01f, tr * 0.015625f - 1.0f, alpha);
    const float a2 = alpha * 0.03125f;  // 2*alpha/64
    float til[4][4];
#pragma unroll
    for (int i = 0; i < 4; ++i) {
      uint2 w = *(const uint2*)(S2 + prow[i]);
      float pt[4] = {rlo(w.x), rhi(w.x), rlo(w.y), rhi(w.y)};
#pragma unroll
      for (int j = 0; j < 4; ++j) {
        float g = fmaf(a2 * x[i][j], pt[j], -sc[i][j]);
        til[i][j] = fmaf(-0.01f, g, x[i][j]);
      }
    }
    prox(til);
  };

  auto chain = [&]() {  // from S0=R(m), S1=T(m): build m15 (af), T3, T15
    AF afm;
    afm.a0 = *(const short8*)(S0 + ra[0]);
    afm.a1 = *(const short8*)(S0 + ra[1]);
    BF8 bm = loadBF(S1);
    AF af2 = mirrorAF(afm, bm);  // m2 (mirror only)
    AF af3 = mirrorAF(af2, bm);  // m3 mirror
    primaryT(af2, bm, S2);       // m3 primary -> T3
    __syncthreads();             // B
    bf3 = loadBF(S2);
    AF af6 = mirrorAF(af3, bf3);    // m6  (B=T3, regs)
    AF af9 = mirrorAF(af6, bf3);    // m9
    AF af12 = mirrorAF(af9, bf3);   // m12
    af = mirrorAF(af12, bf3);       // m15 mirror (kept for front)
    primaryT(af12, bf3, S3);        // m15 primary -> T15
    __syncthreads();                // D
  };
  auto front = [&]() {  // m30, m45, m60 (B=T15), m63 primary -> T63 in S2
    BF8 b15 = loadBF(S3);
    traceP(af, b15);                // free tr(m30)
    AF af30 = mirrorAF(af, b15);    // m30
    AF af45 = mirrorAF(af30, b15);  // m45
    AF af60 = mirrorAF(af45, b15);  // m60
    primaryT(af60, bf3, S2);        // m63 = m60*m3 -> T63
    __syncthreads();                // F
  };

  // ---- iteration 0: alpha == 0 -> grad = -scores ----
  {
    float til[4][4];
#pragma unroll
    for (int i = 0; i < 4; ++i)
#pragma unroll
      for (int j = 0; j < 4; ++j) til[i][j] = fmaf(0.01f, sc[i][j], x[i][j]);
    prox(til);
    stage();
    chain();
  }
  // ---- iterations 1..48 ----
  for (int it = 0; it < 48; ++it) {
    front();
    gradprox();
    stage();
    chain();
  }
  // ---- iteration 49: no trailing stage/chain ----
  front();
  gradprox();

  float* dst = out + (size_t)blockIdx.x * 4096;
#pragma unroll
  for (int i = 0; i < 4; ++i) {
    f32x4 v;
#pragma unroll
    for (int j = 0; j < 4; ++j) v[j] = (x[i][j] > 0.5f) ? x[i][j] : 0.0f;
    *(f32x4*)(dst + (r0 + i) * 64 + c0) = v;
  }
}

extern "C" void kernel_launch(void* const* d_in, const int* in_sizes, int n_in,
                              void* d_out, int out_size, void* d_ws,
                              size_t ws_size, hipStream_t stream) {
  const float* adj = (const float*)d_in[0];
  float* out = (float*)d_out;
  const int nbatch = in_sizes[0] / 4096;  // 512
  dag_iter_kernel<<<nbatch, 256, 0, stream>>>(adj, out);
}

// Round 7
// 213.123 us; speedup vs baseline: 2.6542x; 1.1295x over previous
//
#include <hip/hip_runtime.h>
#include <stdint.h>

// ROUND-7: R6 structure + three micro-cuts:
//  (a) diagonal elementwise-patch mapping c0 = 4*((g4+l15)&15): spreads the
//      stage-write / gradprox-read bank index over all 8 quads (was 4 -> 2x
//      conflict), verified by enumeration (~4 lanes per 2-bank slot).
//  (b) prox via fminf/fmaxf -> v_med3_f32 (+|x| as src modifier): 4->2 VALU/elem.
//  (c) s_setprio(1) around MFMA clusters (T5): chain-critical MFMA wins issue
//      arbitration vs the de-phased co-resident block's VALU/LDS phase.
//
// Power chain (R6, proven): B-operands from 3 synced planes only:
//   T(m): m2=m*m, m3=m2*m ; T3: m6,m9,m12,m15 (+m63=m60*m3) ; T15: m30,m45,m60
// Barriers/iter: A (stage), B (T3), D (T15), F (T63).
// Shell: 512 blocks x 256 thr (4 waves), 2 blocks/CU; wave w owns row band w;
// mirror mfma(b,a) keeps product rows lane-local; 8 pk + 8 permlane rebuild
// the next A-fragments in registers (R5).
//
// Plane format: bf16, stride 64, XOR-swizzled:
//   element [X][Y] at short-index X*64 + (((Y>>3) ^ (X&7))<<3) + (Y&7)
//   T-plane of M: plane[X=c][Y=r] = M[r][c].
#define PL 4096  // shorts per plane

typedef unsigned int u32;
typedef unsigned short u16;
typedef float f32x4 __attribute__((ext_vector_type(4)));
typedef short short8 __attribute__((ext_vector_type(8)));
typedef unsigned int u32x2 __attribute__((ext_vector_type(2)));

__device__ __forceinline__ u32 prm(u32 a, u32 b, u32 s) {
  return __builtin_amdgcn_perm(a, b, s);
}
__device__ __forceinline__ u32 pk(float f0, float f1) {  // {bf16 f0, bf16 f1}
  return prm(__float_as_uint(f1), __float_as_uint(f0), 0x07060302u);
}
__device__ __forceinline__ float rlo(u32 w) { return __uint_as_float(w << 16); }
__device__ __forceinline__ float rhi(u32 w) {
  return __uint_as_float(w & 0xffff0000u);
}
__device__ __forceinline__ short8 mk8(u32 w0, u32 w1, u32 w2, u32 w3) {
  union {
    u32 w[4];
    short8 s;
  } u;
  u.w[0] = w0;
  u.w[1] = w1;
  u.w[2] = w2;
  u.w[3] = w3;
  return u.s;
}
__device__ __forceinline__ void dot8(short8 a, short8 b, float& part) {
  union {
    short8 s;
    u32 w[4];
  } ua, ub;
  ua.s = a;
  ub.s = b;
#pragma unroll
  for (int w = 0; w < 4; ++w) {
    part = fmaf(rlo(ua.w[w]), rlo(ub.w[w]), part);
    part = fmaf(rhi(ua.w[w]), rhi(ub.w[w]), part);
  }
}
__device__ __forceinline__ f32x4 MF(short8 a, short8 b, f32x4 c) {
  return __builtin_amdgcn_mfma_f32_16x16x32_bf16(a, b, c, 0, 0, 0);
}

struct AF {
  short8 a0, a1;
};  // A-frags of the wave's row band: k-halves 0..31, 32..63
struct BF8 {
  short8 b[4][2];
};  // B-frags: 4 col tiles x 2 k-halves

// Group-level redistribution (16-lane groups g=0..3 of the wave):
//   x = [U@g0, U@g2, V@g0, V@g2], y = [U@g1, U@g3, V@g1, V@g3]
__device__ __forceinline__ void dist2(u32 U, u32 V, u32& x, u32& y) {
  u32x2 s = __builtin_amdgcn_permlane32_swap(U, V, false, false);
  // s[0] = [U0,U1,V0,V1], s[1] = [U2,U3,V2,V3]
#if __has_builtin(__builtin_amdgcn_permlane16_swap)
  u32x2 t = __builtin_amdgcn_permlane16_swap(s[0], s[1], false, false);
  x = t[0];  // [U0,U2,V0,V2]
  y = t[1];  // [U1,U3,V1,V3]
#else
  u32 a = s[0], b = s[1];
  u32 bx = (u32)__shfl_xor((int)b, 16);
  u32 ax = (u32)__shfl_xor((int)a, 16);
  const bool odd = ((threadIdx.x >> 4) & 1) != 0;
  x = odd ? bx : a;
  y = odd ? b : ax;
#endif
}

// Mirror acc (4 tiles, lane = row 16w+l15, cols 16b+4g+{0..3}) -> A-frags
// (lane = row, af[kh] word j = cols 32kh+8g+2j+{0,1}).
__device__ __forceinline__ AF macc_to_af(const f32x4 (&m)[4]) {
  u32 P0[4], P1[4];
#pragma unroll
  for (int b = 0; b < 4; ++b) {
    P0[b] = pk(m[b][0], m[b][1]);
    P1[b] = pk(m[b][2], m[b][3]);
  }
  u32 W0[4], W1[4];
  dist2(P0[0], P0[1], W0[0], W0[2]);
  dist2(P1[0], P1[1], W0[1], W0[3]);
  dist2(P0[2], P0[3], W1[0], W1[2]);
  dist2(P1[2], P1[3], W1[1], W1[3]);
  AF r;
  r.a0 = mk8(W0[0], W0[1], W0[2], W0[3]);
  r.a1 = mk8(W1[0], W1[1], W1[2], W1[3]);
  return r;
}

__global__ __launch_bounds__(256, 2) void dag_iter_kernel(
    const float* __restrict__ adj, float* __restrict__ out) {
  __shared__ __align__(16) u16 BUF[4 * PL];
  __shared__ float red[4];
  u16* S0 = BUF;
  u16* S1 = BUF + PL;
  u16* S2 = BUF + 2 * PL;
  u16* S3 = BUF + 3 * PL;

  // De-phase the two co-resident blocks on a CU.
  if ((blockIdx.x >> 8) & 1) __builtin_amdgcn_s_sleep(11);

  const int tid = (int)threadIdx.x;
  const int lane = tid & 63;
  const int wv = tid >> 6;  // row band 0..3
  const int l15 = lane & 15;
  const int grp = lane >> 4;
  const int l7 = l15 & 7;
  // Diagonal 4x4 patch mapping: r0 = 4*(tid&15), c0 = 4*((g4+l15)&15).
  const int r0 = (tid & 15) << 2;
  const int c0 = (((tid >> 4) + (tid & 15)) & 15) << 2;

  // A-frag read (c1 only, from R(m)): row 16w+l15, k-chunk 4kh+grp.
  int ra[2];
#pragma unroll
  for (int kh = 0; kh < 2; ++kh)
    ra[kh] = (16 * wv + l15) * 64 + ((((kh << 2) + grp) ^ l7) << 3);
  // B-frag reads from a T-plane: tile b rows 16b+l15 (row&7 == l7).
  int rb[4][2];
#pragma unroll
  for (int b = 0; b < 4; ++b)
#pragma unroll
    for (int kh = 0; kh < 2; ++kh)
      rb[b][kh] = (16 * b + l15) * 64 + ((((kh << 2) + grp) ^ l7) << 3);
  // Primary-acc T-plane store: T[16b+l15][16w+4grp+{0..3}] (uint2).
  int sT[4];
#pragma unroll
  for (int b = 0; b < 4; ++b)
    sT[b] = (16 * b + l15) * 64 + (((2 * wv + (grp >> 1)) ^ l7) << 3) +
            ((grp & 1) << 2);
  // Elementwise patch addresses.
  int prow[4], pcol[4];
#pragma unroll
  for (int i = 0; i < 4; ++i) {
    prow[i] = (r0 + i) * 64 + ((((c0 >> 3) ^ ((r0 + i) & 7))) << 3) + (c0 & 7);
    pcol[i] = (c0 + i) * 64 + ((((r0 >> 3) ^ ((c0 + i) & 7))) << 3) + (r0 & 7);
  }

  const float* src = adj + (size_t)blockIdx.x * 4096;
  float x[4][4], sc[4][4];
#pragma unroll
  for (int i = 0; i < 4; ++i) {
    f32x4 v = *(const f32x4*)(src + (r0 + i) * 64 + c0);
#pragma unroll
    for (int j = 0; j < 4; ++j) {
      x[i][j] = v[j];
      sc[i][j] = (v[j] > 0.5f) ? v[j] : 0.0f;
    }
  }
  float alpha = 0.0f;
  AF af;    // af(m15): chain -> front
  BF8 bf3;  // B-frags of m3 (T3): reg cache, chain -> m63 primary

  auto loadBF = [&](const u16* P) {
    BF8 f;
#pragma unroll
    for (int b = 0; b < 4; ++b) {
      f.b[b][0] = *(const short8*)(P + rb[b][0]);
      f.b[b][1] = *(const short8*)(P + rb[b][1]);
    }
    return f;
  };
  auto mirrorAF = [&](const AF& a, const BF8& bf) {  // rows of A*M -> regs
    const f32x4 Z = {0.0f, 0.0f, 0.0f, 0.0f};
    f32x4 m[4];
    __builtin_amdgcn_s_setprio(1);
#pragma unroll
    for (int b = 0; b < 4; ++b) {
      m[b] = MF(bf.b[b][0], a.a0, Z);
      m[b] = MF(bf.b[b][1], a.a1, m[b]);
    }
    __builtin_amdgcn_s_setprio(0);
    return macc_to_af(m);
  };
  auto primaryT = [&](const AF& a, const BF8& bf, u16* P) {  // cols -> T-plane
    const f32x4 Z = {0.0f, 0.0f, 0.0f, 0.0f};
    f32x4 p[4];
    __builtin_amdgcn_s_setprio(1);
#pragma unroll
    for (int b = 0; b < 4; ++b) {
      p[b] = MF(a.a0, bf.b[b][0], Z);
      p[b] = MF(a.a1, bf.b[b][1], p[b]);
    }
    __builtin_amdgcn_s_setprio(0);
#pragma unroll
    for (int b = 0; b < 4; ++b)
      *(uint2*)(P + sT[b]) = make_uint2(pk(p[b][0], p[b][1]), pk(p[b][2], p[b][3]));
  };
  auto traceP = [&](const AF& a, const BF8& bf) {  // tr(m30) from m15 frags
    short8 c0s = bf.b[0][0], c1s = bf.b[0][1];
    if (wv == 1) {
      c0s = bf.b[1][0];
      c1s = bf.b[1][1];
    } else if (wv == 2) {
      c0s = bf.b[2][0];
      c1s = bf.b[2][1];
    } else if (wv == 3) {
      c0s = bf.b[3][0];
      c1s = bf.b[3][1];
    }
    float part = 0.0f;
    dot8(a.a0, c0s, part);
    dot8(a.a1, c1s, part);
#pragma unroll
    for (int off = 1; off < 64; off <<= 1) part += __shfl_xor(part, off);
    if (lane == 0) red[wv] = part;
  };

  auto prox = [&](float til[4][4]) {
#pragma unroll
    for (int i = 0; i < 4; ++i)
#pragma unroll
      for (int j = 0; j < 4; ++j) {
        float ax = fabsf(til[i][j]) - 2e-5f;
        x[i][j] = fminf(fmaxf(ax, 0.0f), 1.0f);  // -> v_med3_f32
      }
  };
  auto stage = [&]() {  // m = I + x.*x/64 -> S0 (R-plane), S1 (T-plane)
    float m[4][4];
#pragma unroll
    for (int i = 0; i < 4; ++i)
#pragma unroll
      for (int j = 0; j < 4; ++j)
        m[i][j] = fmaf(x[i][j] * x[i][j], 0.015625f,
                       (r0 + i == c0 + j) ? 1.0f : 0.0f);
#pragma unroll
    for (int i = 0; i < 4; ++i)
      *(uint2*)(S0 + prow[i]) =
          make_uint2(pk(m[i][0], m[i][1]), pk(m[i][2], m[i][3]));
#pragma unroll
    for (int j = 0; j < 4; ++j)
      *(uint2*)(S1 + pcol[j]) =
          make_uint2(pk(m[0][j], m[1][j]), pk(m[2][j], m[3][j]));
    __syncthreads();  // A
  };
  auto gradprox = [&]() {  // polyT[i][j] = T63-plane[r0+i][c0+j] (S2)
    float tr = red[0] + red[1] + red[2] + red[3];
    alpha = fmaf(0.01f, tr * 0.015625f - 1.0f, alpha);
    const float a2 = alpha * 0.03125f;  // 2*alpha/64
    float til[4][4];
#pragma unroll
    for (int i = 0; i < 4; ++i) {
      uint2 w = *(const uint2*)(S2 + prow[i]);
      float pt[4] = {rlo(w.x), rhi(w.x), rlo(w.y), rhi(w.y)};
#pragma unroll
      for (int j = 0; j < 4; ++j) {
        float g = fmaf(a2 * x[i][j], pt[j], -sc[i][j]);
        til[i][j] = fmaf(-0.01f, g, x[i][j]);
      }
    }
    prox(til);
  };

  auto chain = [&]() {  // from S0=R(m), S1=T(m): build m15 (af), T3, T15
    AF afm;
    afm.a0 = *(const short8*)(S0 + ra[0]);
    afm.a1 = *(const short8*)(S0 + ra[1]);
    BF8 bm = loadBF(S1);
    AF af2 = mirrorAF(afm, bm);  // m2 (mirror only)
    AF af3 = mirrorAF(af2, bm);  // m3 mirror
    primaryT(af2, bm, S2);       // m3 primary -> T3
    __syncthreads();             // B
    bf3 = loadBF(S2);
    AF af6 = mirrorAF(af3, bf3);   // m6  (B=T3, regs)
    AF af9 = mirrorAF(af6, bf3);   // m9
    AF af12 = mirrorAF(af9, bf3);  // m12
    af = mirrorAF(af12, bf3);      // m15 mirror (kept for front)
    primaryT(af12, bf3, S3);       // m15 primary -> T15
    __syncthreads();               // D
  };
  auto front = [&]() {  // m30, m45, m60 (B=T15), m63 primary -> T63 in S2
    BF8 b15 = loadBF(S3);
    traceP(af, b15);                // free tr(m30)
    AF af30 = mirrorAF(af, b15);    // m30
    AF af45 = mirrorAF(af30, b15);  // m45
    AF af60 = mirrorAF(af45, b15);  // m60
    primaryT(af60, bf3, S2);        // m63 = m60*m3 -> T63
    __syncthreads();                // F
  };

  // ---- iteration 0: alpha == 0 -> grad = -scores ----
  {
    float til[4][4];
#pragma unroll
    for (int i = 0; i < 4; ++i)
#pragma unroll
      for (int j = 0; j < 4; ++j) til[i][j] = fmaf(0.01f, sc[i][j], x[i][j]);
    prox(til);
    stage();
    chain();
  }
  // ---- iterations 1..48 ----
  for (int it = 0; it < 48; ++it) {
    front();
    gradprox();
    stage();
    chain();
  }
  // ---- iteration 49: no trailing stage/chain ----
  front();
  gradprox();

  float* dst = out + (size_t)blockIdx.x * 4096;
#pragma unroll
  for (int i = 0; i < 4; ++i) {
    f32x4 v;
#pragma unroll
    for (int j = 0; j < 4; ++j) v[j] = (x[i][j] > 0.5f) ? x[i][j] : 0.0f;
    *(f32x4*)(dst + (r0 + i) * 64 + c0) = v;
  }
}

extern "C" void kernel_launch(void* const* d_in, const int* in_sizes, int n_in,
                              void* d_out, int out_size, void* d_ws,
                              size_t ws_size, hipStream_t stream) {
  const float* adj = (const float*)d_in[0];
  float* out = (float*)d_out;
  const int nbatch = in_sizes[0] / 4096;  // 512
  dag_iter_kernel<<<nbatch, 256, 0, stream>>>(adj, out);
}

// Round 8
// 189.872 us; speedup vs baseline: 2.9792x; 1.1225x over previous
//
#include <hip/hip_runtime.h>
#include <stdint.h>

// ROUND-8: permlane-free A-fragment forwarding via k-axis relabeling.
// Fixed permutation pi(16b+4g+j) = 32(b>>1) + 8g + 4(b&1) + j applied to the
// inner (k) axis of EVERY fragment and plane: position p of any fragment
// holds index pi^-1(p). Products are unchanged (both sides of each
// contraction use the same labeling). The mirror accumulator then already
// delivers the next A-fragment order: macc_to_af = 8 pk + register naming,
// ZERO permlanes (was 8 pk + 8 permlane). kh-split (k<32 / k>=32) is
// preserved by pi, so each MFMA contracts the same 32 summands.
// Obligations: T-planes store row r at Y=pi(r) (sT formula); stage writes at
// pi'd Y-quads; patch ownership defined in Y-space (prow/gradprox addressing
// BYTE-IDENTICAL to R7 -> same conflict-free property); global I/O columns =
// pi^-1(Y-quad) (contiguous float4 quads). Read formulas unchanged.
//
// Carried from R7: diagonal patch mapping, med3 prox, setprio around MFMA.
// Power chain (R6): B-operands from 3 synced planes: T(m): m2,m3; T3: m6,m9,
// m12,m15,m63; T15: m30,m45,m60. Barriers/iter: A,B,D,F.
// Shell: 512 blocks x 256 thr (4 waves), 2 blocks/CU; wave w owns row band w.
//
// Plane format: bf16, stride 64, XOR-swizzled:
//   off(X,Y) = X*64 + (((Y>>3) ^ (X&7))<<3) + (Y&7); inner axis Y pi-labeled.
#define PL 4096  // shorts per plane

typedef unsigned int u32;
typedef unsigned short u16;
typedef float f32x4 __attribute__((ext_vector_type(4)));
typedef short short8 __attribute__((ext_vector_type(8)));

__device__ __forceinline__ u32 prm(u32 a, u32 b, u32 s) {
  return __builtin_amdgcn_perm(a, b, s);
}
__device__ __forceinline__ u32 pk(float f0, float f1) {  // {bf16 f0, bf16 f1}
  return prm(__float_as_uint(f1), __float_as_uint(f0), 0x07060302u);
}
__device__ __forceinline__ float rlo(u32 w) { return __uint_as_float(w << 16); }
__device__ __forceinline__ float rhi(u32 w) {
  return __uint_as_float(w & 0xffff0000u);
}
__device__ __forceinline__ short8 mk8(u32 w0, u32 w1, u32 w2, u32 w3) {
  union {
    u32 w[4];
    short8 s;
  } u;
  u.w[0] = w0;
  u.w[1] = w1;
  u.w[2] = w2;
  u.w[3] = w3;
  return u.s;
}
__device__ __forceinline__ void dot8(short8 a, short8 b, float& part) {
  union {
    short8 s;
    u32 w[4];
  } ua, ub;
  ua.s = a;
  ub.s = b;
#pragma unroll
  for (int w = 0; w < 4; ++w) {
    part = fmaf(rlo(ua.w[w]), rlo(ub.w[w]), part);
    part = fmaf(rhi(ua.w[w]), rhi(ub.w[w]), part);
  }
}
__device__ __forceinline__ f32x4 MF(short8 a, short8 b, f32x4 c) {
  return __builtin_amdgcn_mfma_f32_16x16x32_bf16(a, b, c, 0, 0, 0);
}

struct AF {
  short8 a0, a1;
};  // A-frags of the wave's row band: pi-positions [0,32) and [32,64)
struct BF8 {
  short8 b[4][2];
};  // B-frags: 4 col tiles x 2 k-halves (pi-positions)

// Mirror acc tiles b: lane = row 16w+l15; P0[b]=cols 16b+4g+{0,1},
// P1[b]=cols 16b+4g+{2,3}. pi puts these exactly at a0/a1 word slots:
// a0 = {P0[0],P1[0],P0[1],P1[1]}, a1 = {P0[2],P1[2],P0[3],P1[3]}.
__device__ __forceinline__ AF macc_to_af(const f32x4 (&m)[4]) {
  u32 P0[4], P1[4];
#pragma unroll
  for (int b = 0; b < 4; ++b) {
    P0[b] = pk(m[b][0], m[b][1]);
    P1[b] = pk(m[b][2], m[b][3]);
  }
  AF r;
  r.a0 = mk8(P0[0], P1[0], P0[1], P1[1]);
  r.a1 = mk8(P0[2], P1[2], P0[3], P1[3]);
  return r;
}

__global__ __launch_bounds__(256, 2) void dag_iter_kernel(
    const float* __restrict__ adj, float* __restrict__ out) {
  __shared__ __align__(16) u16 BUF[4 * PL];
  __shared__ float red[4];
  u16* S0 = BUF;
  u16* S1 = BUF + PL;
  u16* S2 = BUF + 2 * PL;
  u16* S3 = BUF + 3 * PL;

  // De-phase the two co-resident blocks on a CU.
  if ((blockIdx.x >> 8) & 1) __builtin_amdgcn_s_sleep(11);

  const int tid = (int)threadIdx.x;
  const int lane = tid & 63;
  const int wv = tid >> 6;  // row band 0..3
  const int l15 = lane & 15;
  const int grp = lane >> 4;
  const int l7 = l15 & 7;

  // Elementwise ownership (Y-space diagonal, R7-proven):
  //   row quad rq, Y-quad yq = (g4 + rq) & 15; owned cols = pi^-1(yq-quad).
  const int rq = tid & 15;
  const int r0 = rq << 2;
  const int yq = (((tid >> 4) + rq) & 15);
  const int yb = yq << 2;  // Y-base of owned cols
  // cq: pi^-1 of Y-quad yq -> contiguous col quad 4*cq.
  const int cq = ((yq >> 1) & 3) + ((yq & 1) << 2) + ((yq >> 3) << 3);
  const int c0g = cq << 2;  // global col base
  // pi-quad of the row quad rq (for stage T-write Y placement).
  const int rpq = ((rq & 3) << 1) + ((rq >> 2) & 1) + ((rq >> 3) << 3);
  const int rp0 = rpq << 2;

  // A-frag read (c1 only, from R(m)): row 16wv+l15, pi-position chunks.
  int ra[2];
#pragma unroll
  for (int kh = 0; kh < 2; ++kh)
    ra[kh] = (16 * wv + l15) * 64 + ((((kh << 2) + grp) ^ l7) << 3);
  // B-frag reads from a T-plane (positional, unchanged).
  int rb[4][2];
#pragma unroll
  for (int b = 0; b < 4; ++b)
#pragma unroll
    for (int kh = 0; kh < 2; ++kh)
      rb[b][kh] = (16 * b + l15) * 64 + ((((kh << 2) + grp) ^ l7) << 3);
  // Primary-acc T-plane store: rows 16wv+4grp+{0..3} -> Y-quad
  // pi: Yb = 32*(wv>>1) + 8*grp + 4*(wv&1).
  int sT[4];
#pragma unroll
  for (int b = 0; b < 4; ++b)
    sT[b] = (16 * b + l15) * 64 +
            ((((grp + ((wv >> 1) << 2)) ^ ((16 * b + l15) & 7))) << 3) +
            ((wv & 1) << 2);
  // Patch addresses. prow: X=r0+i, Y-quad=yb (R-write + T63/gradprox read).
  // pcol: X=owned col, Y-quad=rp0 (stage T-write).
  int prow[4], pcol[4];
#pragma unroll
  for (int i = 0; i < 4; ++i) {
    prow[i] = (r0 + i) * 64 + ((((yb >> 3) ^ ((r0 + i) & 7))) << 3) + (yb & 7);
    pcol[i] =
        (c0g + i) * 64 + ((((rp0 >> 3) ^ ((c0g + i) & 7))) << 3) + (rp0 & 7);
  }

  const float* src = adj + (size_t)blockIdx.x * 4096;
  float x[4][4], sc[4][4];
#pragma unroll
  for (int i = 0; i < 4; ++i) {
    f32x4 v = *(const f32x4*)(src + (r0 + i) * 64 + c0g);
#pragma unroll
    for (int j = 0; j < 4; ++j) {
      x[i][j] = v[j];
      sc[i][j] = (v[j] > 0.5f) ? v[j] : 0.0f;
    }
  }
  float alpha = 0.0f;
  AF af;    // af(m15): chain -> front
  BF8 bf3;  // B-frags of m3 (T3): reg cache, chain -> m63 primary

  auto loadBF = [&](const u16* P) {
    BF8 f;
#pragma unroll
    for (int b = 0; b < 4; ++b) {
      f.b[b][0] = *(const short8*)(P + rb[b][0]);
      f.b[b][1] = *(const short8*)(P + rb[b][1]);
    }
    return f;
  };
  auto mirrorAF = [&](const AF& a, const BF8& bf) {  // rows of A*M -> regs
    const f32x4 Z = {0.0f, 0.0f, 0.0f, 0.0f};
    f32x4 m[4];
    __builtin_amdgcn_s_setprio(1);
#pragma unroll
    for (int b = 0; b < 4; ++b) {
      m[b] = MF(bf.b[b][0], a.a0, Z);
      m[b] = MF(bf.b[b][1], a.a1, m[b]);
    }
    __builtin_amdgcn_s_setprio(0);
    return macc_to_af(m);
  };
  auto primaryT = [&](const AF& a, const BF8& bf, u16* P) {  // cols -> T-plane
    const f32x4 Z = {0.0f, 0.0f, 0.0f, 0.0f};
    f32x4 p[4];
    __builtin_amdgcn_s_setprio(1);
#pragma unroll
    for (int b = 0; b < 4; ++b) {
      p[b] = MF(a.a0, bf.b[b][0], Z);
      p[b] = MF(a.a1, bf.b[b][1], p[b]);
    }
    __builtin_amdgcn_s_setprio(0);
#pragma unroll
    for (int b = 0; b < 4; ++b)
      *(uint2*)(P + sT[b]) =
          make_uint2(pk(p[b][0], p[b][1]), pk(p[b][2], p[b][3]));
  };
  auto traceP = [&](const AF& a, const BF8& bf) {  // tr(m30) from m15 frags
    short8 c0s = bf.b[0][0], c1s = bf.b[0][1];
    if (wv == 1) {
      c0s = bf.b[1][0];
      c1s = bf.b[1][1];
    } else if (wv == 2) {
      c0s = bf.b[2][0];
      c1s = bf.b[2][1];
    } else if (wv == 3) {
      c0s = bf.b[3][0];
      c1s = bf.b[3][1];
    }
    float part = 0.0f;
    dot8(a.a0, c0s, part);
    dot8(a.a1, c1s, part);
#pragma unroll
    for (int off = 1; off < 64; off <<= 1) part += __shfl_xor(part, off);
    if (lane == 0) red[wv] = part;
  };

  auto prox = [&](float til[4][4]) {
#pragma unroll
    for (int i = 0; i < 4; ++i)
#pragma unroll
      for (int j = 0; j < 4; ++j) {
        float ax = fabsf(til[i][j]) - 2e-5f;
        x[i][j] = fminf(fmaxf(ax, 0.0f), 1.0f);  // -> v_med3_f32
      }
  };
  auto stage = [&]() {  // m = I + x.*x/64 -> S0 (R-plane), S1 (T-plane)
    float m[4][4];
#pragma unroll
    for (int i = 0; i < 4; ++i)
#pragma unroll
      for (int j = 0; j < 4; ++j)
        m[i][j] = fmaf(x[i][j] * x[i][j], 0.015625f,
                       (r0 + i == c0g + j) ? 1.0f : 0.0f);
#pragma unroll
    for (int i = 0; i < 4; ++i)
      *(uint2*)(S0 + prow[i]) =
          make_uint2(pk(m[i][0], m[i][1]), pk(m[i][2], m[i][3]));
#pragma unroll
    for (int j = 0; j < 4; ++j)
      *(uint2*)(S1 + pcol[j]) =
          make_uint2(pk(m[0][j], m[1][j]), pk(m[2][j], m[3][j]));
    __syncthreads();  // A
  };
  auto gradprox = [&]() {  // m63[c][r] for owned (r,c) = T63[X=r][Y=yb+j]
    float tr = red[0] + red[1] + red[2] + red[3];
    alpha = fmaf(0.01f, tr * 0.015625f - 1.0f, alpha);
    const float a2 = alpha * 0.03125f;  // 2*alpha/64
    float til[4][4];
#pragma unroll
    for (int i = 0; i < 4; ++i) {
      uint2 w = *(const uint2*)(S2 + prow[i]);
      float pt[4] = {rlo(w.x), rhi(w.x), rlo(w.y), rhi(w.y)};
#pragma unroll
      for (int j = 0; j < 4; ++j) {
        float g = fmaf(a2 * x[i][j], pt[j], -sc[i][j]);
        til[i][j] = fmaf(-0.01f, g, x[i][j]);
      }
    }
    prox(til);
  };

  auto chain = [&]() {  // from S0=R(m), S1=T(m): build m15 (af), T3, T15
    AF afm;
    afm.a0 = *(const short8*)(S0 + ra[0]);
    afm.a1 = *(const short8*)(S0 + ra[1]);
    BF8 bm = loadBF(S1);
    AF af2 = mirrorAF(afm, bm);  // m2 (mirror only)
    AF af3 = mirrorAF(af2, bm);  // m3 mirror
    primaryT(af2, bm, S2);       // m3 primary -> T3
    __syncthreads();             // B
    bf3 = loadBF(S2);
    AF af6 = mirrorAF(af3, bf3);   // m6  (B=T3, regs)
    AF af9 = mirrorAF(af6, bf3);   // m9
    AF af12 = mirrorAF(af9, bf3);  // m12
    af = mirrorAF(af12, bf3);      // m15 mirror (kept for front)
    primaryT(af12, bf3, S3);       // m15 primary -> T15
    __syncthreads();               // D
  };
  auto front = [&]() {  // m30, m45, m60 (B=T15), m63 primary -> T63 in S2
    BF8 b15 = loadBF(S3);
    traceP(af, b15);                // free tr(m30)
    AF af30 = mirrorAF(af, b15);    // m30
    AF af45 = mirrorAF(af30, b15);  // m45
    AF af60 = mirrorAF(af45, b15);  // m60
    primaryT(af60, bf3, S2);        // m63 = m60*m3 -> T63
    __syncthreads();                // F
  };

  // ---- iteration 0: alpha == 0 -> grad = -scores ----
  {
    float til[4][4];
#pragma unroll
    for (int i = 0; i < 4; ++i)
#pragma unroll
      for (int j = 0; j < 4; ++j) til[i][j] = fmaf(0.01f, sc[i][j], x[i][j]);
    prox(til);
    stage();
    chain();
  }
  // ---- iterations 1..48 ----
  for (int it = 0; it < 48; ++it) {
    front();
    gradprox();
    stage();
    chain();
  }
  // ---- iteration 49: no trailing stage/chain ----
  front();
  gradprox();

  float* dst = out + (size_t)blockIdx.x * 4096;
#pragma unroll
  for (int i = 0; i < 4; ++i) {
    f32x4 v;
#pragma unroll
    for (int j = 0; j < 4; ++j) v[j] = (x[i][j] > 0.5f) ? x[i][j] : 0.0f;
    *(f32x4*)(dst + (r0 + i) * 64 + c0g) = v;
  }
}

extern "C" void kernel_launch(void* const* d_in, const int* in_sizes, int n_in,
                              void* d_out, int out_size, void* d_ws,
                              size_t ws_size, hipStream_t stream) {
  const float* adj = (const float*)d_in[0];
  float* out = (float*)d_out;
  const int nbatch = in_sizes[0] / 4096;  // 512
  dag_iter_kernel<<<nbatch, 256, 0, stream>>>(adj, out);
}

// Round 9
// 183.062 us; speedup vs baseline: 3.0900x; 1.0372x over previous
//
#include <hip/hip_runtime.h>
#include <stdint.h>

// ROUND-9: column-strided ownership + register-local gradprox.
// Ownership: lane (w=wave, g=lane>>4, l15=lane&15) owns x[r][c] for
//   c = 16w+l15 (fixed), r in {16b+4g+j : b,j=0..3}  (x[b][j] registers).
// This matches the mirror-accumulator layout: the m63 MIRROR acc holds
// m63[16w+l15][16b+4g+j] = m63[c][r] per lane -> gradprox reads f32 regs,
// T63 plane + its stores/loads + barrier-F data handoff DELETED.
// stage's T(m) write: lane's 16 elements at X=c fixed, Y=pi(r) = two
// contiguous 8-runs -> 2x ds_write_b128 (was 8 uint2 over two planes).
// R(m) plane deleted: chain head af(m) = mirror(bm, afI) with afI = one-hot
// identity A-fragment (1.0 at pi-position pi(16w+l15)) -> exact rows of m.
// Barrier E (after trace red[] write, padded by m30..m63) replaces F.
//
// Carried: R8 pi-relabeled fragments (permlane-free macc_to_af), R7 med3
// prox + setprio, R6 3-plane power chain:
//   T(m): m2,m3 ; T3: m6,m9,m12,m15,m63 ; T15: m30,m45,m60
// Barriers/iter: A (stage), B (T3), D (T15), E (red sync only).
// Shell: 512 blocks x 256 thr (4 waves), 2 blocks/CU; wave w owns row band w.
// Plane format: bf16, stride 64, XOR-swizzled:
//   off(X,Y) = X*64 + (((Y>>3) ^ (X&7))<<3) + (Y&7); Y-axis pi-labeled,
//   pi(16b+4g+j) = 32(b>>1)+8g+4(b&1)+j.
#define PL 4096  // shorts per plane

typedef unsigned int u32;
typedef unsigned short u16;
typedef float f32x4 __attribute__((ext_vector_type(4)));
typedef short short8 __attribute__((ext_vector_type(8)));

__device__ __forceinline__ u32 prm(u32 a, u32 b, u32 s) {
  return __builtin_amdgcn_perm(a, b, s);
}
__device__ __forceinline__ u32 pk(float f0, float f1) {  // {bf16 f0, bf16 f1}
  return prm(__float_as_uint(f1), __float_as_uint(f0), 0x07060302u);
}
__device__ __forceinline__ float rlo(u32 w) { return __uint_as_float(w << 16); }
__device__ __forceinline__ float rhi(u32 w) {
  return __uint_as_float(w & 0xffff0000u);
}
__device__ __forceinline__ short8 mk8(u32 w0, u32 w1, u32 w2, u32 w3) {
  union {
    u32 w[4];
    short8 s;
  } u;
  u.w[0] = w0;
  u.w[1] = w1;
  u.w[2] = w2;
  u.w[3] = w3;
  return u.s;
}
__device__ __forceinline__ void dot8(short8 a, short8 b, float& part) {
  union {
    short8 s;
    u32 w[4];
  } ua, ub;
  ua.s = a;
  ub.s = b;
#pragma unroll
  for (int w = 0; w < 4; ++w) {
    part = fmaf(rlo(ua.w[w]), rlo(ub.w[w]), part);
    part = fmaf(rhi(ua.w[w]), rhi(ub.w[w]), part);
  }
}
__device__ __forceinline__ f32x4 MF(short8 a, short8 b, f32x4 c) {
  return __builtin_amdgcn_mfma_f32_16x16x32_bf16(a, b, c, 0, 0, 0);
}

struct AF {
  short8 a0, a1;
};  // A-frags of the wave's row band: pi-positions [0,32) and [32,64)
struct BF8 {
  short8 b[4][2];
};  // B-frags: 4 col tiles x 2 k-halves (pi-positions)

// Mirror acc tiles b: lane = row 16w+l15; P0[b]=cols 16b+4g+{0,1},
// P1[b]=cols 16b+4g+{2,3}. pi puts these exactly at a0/a1 word slots.
__device__ __forceinline__ AF macc_to_af(const f32x4 (&m)[4]) {
  u32 P0[4], P1[4];
#pragma unroll
  for (int b = 0; b < 4; ++b) {
    P0[b] = pk(m[b][0], m[b][1]);
    P1[b] = pk(m[b][2], m[b][3]);
  }
  AF r;
  r.a0 = mk8(P0[0], P1[0], P0[1], P1[1]);
  r.a1 = mk8(P0[2], P1[2], P0[3], P1[3]);
  return r;
}

__global__ __launch_bounds__(256, 2) void dag_iter_kernel(
    const float* __restrict__ adj, float* __restrict__ out) {
  __shared__ __align__(16) u16 BUF[3 * PL];
  __shared__ float red[4];
  u16* SM = BUF;           // T(m)
  u16* P1 = BUF + PL;      // T3
  u16* P2 = BUF + 2 * PL;  // T15

  // De-phase the two co-resident blocks on a CU.
  if ((blockIdx.x >> 8) & 1) __builtin_amdgcn_s_sleep(11);

  const int tid = (int)threadIdx.x;
  const int lane = tid & 63;
  const int wv = tid >> 6;  // row band 0..3
  const int l15 = lane & 15;
  const int grp = lane >> 4;
  const int l7 = l15 & 7;

  const int c = 16 * wv + l15;  // owned column
  int rb[4][2];
#pragma unroll
  for (int b = 0; b < 4; ++b)
#pragma unroll
    for (int kh = 0; kh < 2; ++kh)
      rb[b][kh] = (16 * b + l15) * 64 + ((((kh << 2) + grp) ^ l7) << 3);
  int sT[4];
#pragma unroll
  for (int b = 0; b < 4; ++b)
    sT[b] = (16 * b + l15) * 64 +
            ((((grp + ((wv >> 1) << 2)) ^ ((16 * b + l15) & 7))) << 3) +
            ((wv & 1) << 2);
  int stT[2];
#pragma unroll
  for (int h = 0; h < 2; ++h)
    stT[h] = c * 64 + ((((h << 2) + grp) ^ (c & 7)) << 3);

  // afI: one-hot identity A-fragment, 1.0bf16 at pi-position pi(c).
  AF afI;
  {
    const bool mine = (grp == (l15 >> 2));
    const int s = ((wv & 1) << 2) + (l15 & 3);  // slot 0..7
    const u32 onev = (s & 1) ? 0x3F800000u : 0x00003F80u;
    u32 w[4];
#pragma unroll
    for (int k = 0; k < 4; ++k) w[k] = (mine && ((s >> 1) == k)) ? onev : 0u;
    short8 hot = mk8(w[0], w[1], w[2], w[3]);
    short8 zero = mk8(0u, 0u, 0u, 0u);
    afI.a0 = (wv < 2) ? hot : zero;
    afI.a1 = (wv < 2) ? zero : hot;
  }

  // x[b][j] = x[r][c], r = 16b+4g+j.
  const float* src = adj + (size_t)blockIdx.x * 4096;
  float x[4][4], sc[4][4];
#pragma unroll
  for (int b = 0; b < 4; ++b)
#pragma unroll
    for (int j = 0; j < 4; ++j) {
      float v = src[(16 * b + 4 * grp + j) * 64 + c];
      x[b][j] = v;
      sc[b][j] = (v > 0.5f) ? v : 0.0f;
    }
  float alpha = 0.0f;
  AF af;           // af(m15): chain -> front
  BF8 bf3;         // B-frags of m3 (T3): chain -> m63
  f32x4 acc63[4];  // m63 mirror acc (f32), front -> gradprox

  auto loadBF = [&](const u16* P) {
    BF8 f;
#pragma unroll
    for (int b = 0; b < 4; ++b) {
      f.b[b][0] = *(const short8*)(P + rb[b][0]);
      f.b[b][1] = *(const short8*)(P + rb[b][1]);
    }
    return f;
  };
  auto mirrorAF = [&](const AF& a, const BF8& bf) {  // rows of A*M -> regs
    const f32x4 Z = {0.0f, 0.0f, 0.0f, 0.0f};
    f32x4 m[4];
    __builtin_amdgcn_s_setprio(1);
#pragma unroll
    for (int b = 0; b < 4; ++b) {
      m[b] = MF(bf.b[b][0], a.a0, Z);
      m[b] = MF(bf.b[b][1], a.a1, m[b]);
    }
    __builtin_amdgcn_s_setprio(0);
    return macc_to_af(m);
  };
  auto primaryT = [&](const AF& a, const BF8& bf, u16* P) {  // cols -> T-plane
    const f32x4 Z = {0.0f, 0.0f, 0.0f, 0.0f};
    f32x4 p[4];
    __builtin_amdgcn_s_setprio(1);
#pragma unroll
    for (int b = 0; b < 4; ++b) {
      p[b] = MF(a.a0, bf.b[b][0], Z);
      p[b] = MF(a.a1, bf.b[b][1], p[b]);
    }
    __builtin_amdgcn_s_setprio(0);
#pragma unroll
    for (int b = 0; b < 4; ++b)
      *(uint2*)(P + sT[b]) =
          make_uint2(pk(p[b][0], p[b][1]), pk(p[b][2], p[b][3]));
  };
  auto traceP = [&](const AF& a, const BF8& bf) {  // tr(m30) from m15 frags
    short8 c0s = bf.b[0][0], c1s = bf.b[0][1];
    if (wv == 1) {
      c0s = bf.b[1][0];
      c1s = bf.b[1][1];
    } else if (wv == 2) {
      c0s = bf.b[2][0];
      c1s = bf.b[2][1];
    } else if (wv == 3) {
      c0s = bf.b[3][0];
      c1s = bf.b[3][1];
    }
    float part = 0.0f;
    dot8(a.a0, c0s, part);
    dot8(a.a1, c1s, part);
#pragma unroll
    for (int off = 1; off < 64; off <<= 1) part += __shfl_xor(part, off);
    if (lane == 0) red[wv] = part;
  };

  auto prox = [&](float til[4][4]) {
#pragma unroll
    for (int b = 0; b < 4; ++b)
#pragma unroll
      for (int j = 0; j < 4; ++j) {
        float ax = fabsf(til[b][j]) - 2e-5f;
        x[b][j] = fminf(fmaxf(ax, 0.0f), 1.0f);  // -> v_med3_f32
      }
  };
  auto stage = [&]() {  // m = I + x.*x/64 -> T(m)-plane (SM), 2x b128
    float m[4][4];
#pragma unroll
    for (int b = 0; b < 4; ++b)
#pragma unroll
      for (int j = 0; j < 4; ++j)
        m[b][j] = fmaf(x[b][j] * x[b][j], 0.015625f,
                       (b == wv && 4 * grp + j == l15) ? 1.0f : 0.0f);
#pragma unroll
    for (int h = 0; h < 2; ++h)
      *(short8*)(SM + stT[h]) =
          mk8(pk(m[2 * h][0], m[2 * h][1]), pk(m[2 * h][2], m[2 * h][3]),
              pk(m[2 * h + 1][0], m[2 * h + 1][1]),
              pk(m[2 * h + 1][2], m[2 * h + 1][3]));
    __syncthreads();  // A
  };
  auto gradprox = [&]() {  // m63^T patch = acc63 f32 regs; alpha from red
    float tr = red[0] + red[1] + red[2] + red[3];
    alpha = fmaf(0.01f, tr * 0.015625f - 1.0f, alpha);
    const float a2 = alpha * 0.03125f;  // 2*alpha/64
    float til[4][4];
#pragma unroll
    for (int b = 0; b < 4; ++b)
#pragma unroll
      for (int j = 0; j < 4; ++j) {
        float g = fmaf(a2 * x[b][j], acc63[b][j], -sc[b][j]);
        til[b][j] = fmaf(-0.01f, g, x[b][j]);
      }
    prox(til);
  };

  auto chain = [&]() {  // from SM=T(m): build m15 (af), T3, T15
    BF8 bm = loadBF(SM);
    AF afm = mirrorAF(afI, bm);  // rows of m via identity one-hot
    AF af2 = mirrorAF(afm, bm);  // m2
    AF af3 = mirrorAF(af2, bm);  // m3 rows
    primaryT(af2, bm, P1);       // m3 cols -> T3
    __syncthreads();             // B
    bf3 = loadBF(P1);
    AF af6 = mirrorAF(af3, bf3);   // m6
    AF af9 = mirrorAF(af6, bf3);   // m9
    AF af12 = mirrorAF(af9, bf3);  // m12
    af = mirrorAF(af12, bf3);      // m15 rows (kept for front)
    primaryT(af12, bf3, P2);       // m15 cols -> T15
    __syncthreads();               // D
  };
  auto front = [&]() {  // m30,m45,m60 (B=T15); m63 mirror acc (f32, no pack)
    BF8 b15 = loadBF(P2);
    traceP(af, b15);  // red[wv] = band part of tr(m30)
    __syncthreads();  // E (red sync; padded by the mirrors below)
    AF af30 = mirrorAF(af, b15);
    AF af45 = mirrorAF(af30, b15);
    AF af60 = mirrorAF(af45, b15);
    const f32x4 Z = {0.0f, 0.0f, 0.0f, 0.0f};
    __builtin_amdgcn_s_setprio(1);
#pragma unroll
    for (int b = 0; b < 4; ++b) {
      acc63[b] = MF(bf3.b[b][0], af60.a0, Z);
      acc63[b] = MF(bf3.b[b][1], af60.a1, acc63[b]);
    }
    __builtin_amdgcn_s_setprio(0);
  };

  // ---- iteration 0: alpha == 0 -> grad = -scores ----
  {
    float til[4][4];
#pragma unroll
    for (int b = 0; b < 4; ++b)
#pragma unroll
      for (int j = 0; j < 4; ++j) til[b][j] = fmaf(0.01f, sc[b][j], x[b][j]);
    prox(til);
    stage();
    chain();
  }
  // ---- iterations 1..48 ----
  for (int it = 0; it < 48; ++it) {
    front();
    gradprox();
    stage();
    chain();
  }
  // ---- iteration 49: no trailing stage/chain ----
  front();
  gradprox();

  float* dst = out + (size_t)blockIdx.x * 4096;
#pragma unroll
  for (int b = 0; b < 4; ++b)
#pragma unroll
    for (int j = 0; j < 4; ++j) {
      float v = x[b][j];
      dst[(16 * b + 4 * grp + j) * 64 + c] = (v > 0.5f) ? v : 0.0f;
    }
}

extern "C" void kernel_launch(void* const* d_in, const int* in_sizes, int n_in,
                              void* d_out, int out_size, void* d_ws,
                              size_t ws_size, hipStream_t stream) {
  const float* adj = (const float*)d_in[0];
  float* out = (float*)d_out;
  const int nbatch = in_sizes[0] / 4096;  // 512
  dag_iter_kernel<<<nbatch, 256, 0, stream>>>(adj, out);
}